// Round 5
// baseline (208.760 us; speedup 1.0000x reference)
//
#include <hip/hip_runtime.h>
#include <math.h>

#define S_LEN 8192
#define DHEAD 64
#define NBATCH 4
#define BQ 128
#define BK 32
#define KIT 64            // 2048 keys per kq-quarter / BK

typedef unsigned short u16;
typedef unsigned int u32;
typedef __attribute__((ext_vector_type(8))) short short8;
typedef __attribute__((ext_vector_type(4))) float f32x4;

union U16x8 { int4 i4; short8 s8; u32 w[4]; };

#if __has_builtin(__builtin_amdgcn_exp2f)
#define EXP2(x) __builtin_amdgcn_exp2f(x)
#else
#define EXP2(x) exp2f(x)
#endif

// float -> bf16 RNE (prep path only)
__device__ __forceinline__ u16 f2b(float f) {
    u32 u = __float_as_uint(f);
    u32 r = (u + 0x7fffu + ((u >> 16) & 1u)) >> 16;
    return (u16)r;
}

// two floats -> packed bf16x2 (a low), round-half-up: 2 add + 1 perm
__device__ __forceinline__ u32 pack2(float a, float b) {
    u32 ua = __float_as_uint(a) + 0x8000u;
    u32 ub = __float_as_uint(b) + 0x8000u;
    return __builtin_amdgcn_perm(ub, ua, 0x07060302u);
}

// ---------------------------------------------------------------------------
// Fused prep: [0,512) V->Vt bf16 [b][d][s]; [512,1024) K->bf16 row-major;
// [1024,1056) Julia bias in f64 (matches numpy), fixed softmax max M=20
// folded in: bias2[k] = log(exp(et*scale)+1e-8)*log2e - 20
// ---------------------------------------------------------------------------
__global__ void prep_kernel(const float* __restrict__ K, const float* __restrict__ V,
                            const float* crp, const float* cip, const float* scp,
                            u16* __restrict__ Kb, u16* __restrict__ Vt,
                            float* __restrict__ bias2) {
    int bid = blockIdx.x, tid = threadIdx.x;
    if (bid < 512) {
        __shared__ float tile[64][65];
        int b = bid >> 7;
        int s0 = (bid & 127) * 64;
        int c4 = (tid & 15) * 4;
        int rr = tid >> 4;
#pragma unroll
        for (int p = 0; p < 4; ++p) {
            int row = p * 16 + rr;
            float4 v = *(const float4*)(V + ((size_t)(b * S_LEN + s0 + row)) * DHEAD + c4);
            tile[row][c4 + 0] = v.x; tile[row][c4 + 1] = v.y;
            tile[row][c4 + 2] = v.z; tile[row][c4 + 3] = v.w;
        }
        __syncthreads();
#pragma unroll
        for (int p = 0; p < 4; ++p) {
            int d = p * 16 + rr;
            u32 lo = (u32)f2b(tile[c4 + 0][d]) | ((u32)f2b(tile[c4 + 1][d]) << 16);
            u32 hi = (u32)f2b(tile[c4 + 2][d]) | ((u32)f2b(tile[c4 + 3][d]) << 16);
            *(uint2*)(Vt + ((size_t)(b * DHEAD + d)) * S_LEN + s0 + c4) = make_uint2(lo, hi);
        }
    } else if (bid < 1024) {
        size_t base = ((size_t)(bid - 512) * 256 + tid) * 16;
#pragma unroll
        for (int j = 0; j < 4; ++j) {
            float4 v = *(const float4*)(K + base + j * 4);
            u32 lo = (u32)f2b(v.x) | ((u32)f2b(v.y) << 16);
            u32 hi = (u32)f2b(v.z) | ((u32)f2b(v.w) << 16);
            *(uint2*)(Kb + base + j * 4) = make_uint2(lo, hi);
        }
    } else {
#pragma clang fp contract(off)
        int i = (bid - 1024) * 256 + tid;
        double cr = (double)crp[0], ci = (double)cip[0], sc = (double)scp[0];
        double step = 4.0 / (double)(S_LEN - 1);
        double x = (i == S_LEN - 1) ? 2.0 : (-2.0 + step * (double)i);
        double zr = x, zi = 0.0, et = 1.0;
        bool esc = false;
        for (int it = 0; it < 64; ++it) {
            double nzr = zr * zr - zi * zi + cr;
            double nzi = 2.0 * zr * zi + ci;
            if (!esc) { zr = nzr; zi = nzi; }
            double m2 = zr * zr + zi * zi;
            if (!esc && m2 > 4.0) { et = (double)it / 64.0; esc = true; }
        }
        double bias = log(exp(et * sc) + 1e-8);
        bias2[i] = (float)(bias * 1.4426950408889634 - 20.0);
    }
}

// ---------------------------------------------------------------------------
// Flash, NO-LDS main loop (fragments gathered straight from L2-resident
// Kb/Vt; K prefetched one iter ahead in registers), fixed-max softmax,
// 4-way in-block split-K:
//   grid 256 (1 block/CU), block 512 = 8 waves = 4 kq x 2 qs; wave: 64 q x
//   2048 keys, BK=32. Zero barriers / LDS / DMA in the loop -> free-running
//   waves overlap VALU/MFMA/VMEM without sync stalls.
//   QK tiles use key-permuted rows (key = 8*(m>>2)+4*kt+(m&3)) so the P
//   C-frag IS the 16x16x32 B-operand layout -> PV in K=32, b128 V gathers.
// ---------------------------------------------------------------------------
__global__ __launch_bounds__(512, 2)
void flash_kernel(const float* __restrict__ Q, const u16* __restrict__ Kb,
                  const u16* __restrict__ Vt, const float* __restrict__ bias2,
                  float* __restrict__ Out) {
    __shared__ __align__(16) char smem[36864];   // merge scratch only

    const int tid = threadIdx.x;
    const int w = tid >> 6, l = tid & 63, low = l & 15, h = l >> 4;
    const int kq = w & 3, qs = w >> 2;

    const int bid = blockIdx.x;
    const int batch = bid & 3;          // XCD-affinity: 2 XCDs per batch
    const int qtile = bid >> 2;         // 0..63
    const int q0 = qtile * BQ + qs * 64;

    // ---- Q fragments (4 x 16 q-rows), scale log2(e)/8 folded ----
    const float qscale = 0.18033688011112042f;
    short8 qfrag[4][2];
#pragma unroll
    for (int qf = 0; qf < 4; ++qf) {
        const float* qrow = Q + ((size_t)(batch * S_LEN + q0 + qf * 16 + low)) * DHEAD + h * 8;
#pragma unroll
        for (int ds = 0; ds < 2; ++ds) {
            f32x4 a = *(const f32x4*)(qrow + ds * 32);
            f32x4 b = *(const f32x4*)(qrow + ds * 32 + 4);
            U16x8 u;
#pragma unroll
            for (int j = 0; j < 4; ++j) {
                u.s8[j]     = (short)f2b(a[j] * qscale);
                u.s8[4 + j] = (short)f2b(b[j] * qscale);
            }
            qfrag[qf][ds] = u.s8;
        }
    }

    // ---- per-lane constant gather offsets (u16 elems) ----
    // K frag: A[m=key][d]; lane holds K[key R][d = ds*32 + 8h..8h+7]
    const u16* Kq = Kb + ((size_t)(batch * S_LEN + kq * 2048)) * 64;
    const u16* Vb = Vt + (size_t)batch * DHEAD * S_LEN + kq * 2048;
    int kfoff[2][2], vfoff[4];
#pragma unroll
    for (int kt = 0; kt < 2; ++kt) {
        const int R = 8 * (low >> 2) + 4 * kt + (low & 3);   // key-permuted row
#pragma unroll
        for (int ds = 0; ds < 2; ++ds)
            kfoff[kt][ds] = R * 64 + ds * 32 + h * 8;
    }
#pragma unroll
    for (int dt = 0; dt < 4; ++dt)
        vfoff[dt] = (dt * 16 + low) * S_LEN + h * 8;

    // ---- K register double-buffer: preload iter 0 ----
    U16x8 kfr[2][2][2];   // [parity][kt][ds]
#pragma unroll
    for (int kt = 0; kt < 2; ++kt)
#pragma unroll
        for (int ds = 0; ds < 2; ++ds)
            kfr[0][kt][ds].i4 = *(const int4*)(Kq + kfoff[kt][ds]);

    f32x4 o[4][4];
#pragma unroll
    for (int qf = 0; qf < 4; ++qf)
#pragma unroll
        for (int dt = 0; dt < 4; ++dt) o[qf][dt] = (f32x4){0, 0, 0, 0};
    float lsum[4] = {0.f, 0.f, 0.f, 0.f};

    // bias pipeline: key = kq*2048 + ki*32 + 8h + 4kt + r
    const float* b2p = bias2 + kq * 2048 + h * 8;
    f32x4 bv0 = *(const f32x4*)b2p;
    f32x4 bv1 = *(const f32x4*)(b2p + 4);
    b2p += BK;

#pragma unroll 2
    for (int ki = 0; ki < KIT; ++ki) {
        const int p = ki & 1;

        // V frags for THIS iter: issued first, consumed after softmax
        U16x8 vf[4];
        const u16* vrow = Vb + ki * BK;
#pragma unroll
        for (int dt = 0; dt < 4; ++dt)
            vf[dt].i4 = *(const int4*)(vrow + vfoff[dt]);

        // next-iter bias (last iter reads past quarter end -> Kb region, unused)
        f32x4 bvn0 = *(const f32x4*)b2p;
        f32x4 bvn1 = *(const f32x4*)(b2p + 4);
        b2p += BK;

        // K frags for NEXT iter (clamped on last)
        const u16* knrow = Kq + (size_t)(ki + 1 < KIT ? ki + 1 : ki) * (BK * 64);
#pragma unroll
        for (int kt = 0; kt < 2; ++kt)
#pragma unroll
            for (int ds = 0; ds < 2; ++ds)
                kfr[p ^ 1][kt][ds].i4 = *(const int4*)(knrow + kfoff[kt][ds]);

        // ---- per kt: QK (bias C-init) then softmax immediately (short st life)
        U16x8 pf[4];
#pragma unroll
        for (int kt = 0; kt < 2; ++kt) {
            const f32x4 binit = kt ? bv1 : bv0;
            f32x4 st[4];
#pragma unroll
            for (int qf = 0; qf < 4; ++qf) {
                f32x4 a = __builtin_amdgcn_mfma_f32_16x16x32_bf16(kfr[p][kt][0].s8, qfrag[qf][0], binit, 0, 0, 0);
                a = __builtin_amdgcn_mfma_f32_16x16x32_bf16(kfr[p][kt][1].s8, qfrag[qf][1], a, 0, 0, 0);
                st[qf] = a;
            }
#pragma unroll
            for (int qf = 0; qf < 4; ++qf) {
                float p0 = EXP2(st[qf][0]), p1 = EXP2(st[qf][1]);
                float p2 = EXP2(st[qf][2]), p3 = EXP2(st[qf][3]);
                lsum[qf] += (p0 + p1) + (p2 + p3);
                pf[qf].w[kt * 2]     = pack2(p0, p1);
                pf[qf].w[kt * 2 + 1] = pack2(p2, p3);
            }
        }
        bv0 = bvn0; bv1 = bvn1;

        // ---- O^T += V^T·P^T (K=32), V-frag shared across 4 q-frags ----
#pragma unroll
        for (int dt = 0; dt < 4; ++dt)
#pragma unroll
            for (int qf = 0; qf < 4; ++qf)
                o[qf][dt] = __builtin_amdgcn_mfma_f32_16x16x32_bf16(vf[dt].s8, pf[qf].s8, o[qf][dt], 0, 0, 0);
    }

    // ---- finalize l (one cross-lane reduce per q-frag) ----
#pragma unroll
    for (int qf = 0; qf < 4; ++qf) {
        lsum[qf] += __shfl_xor(lsum[qf], 16, 64);
        lsum[qf] += __shfl_xor(lsum[qf], 32, 64);
    }

    // ---- split-K merge: partials add linearly (fixed max). 3 stages. ----
    float* MO = (float*)smem;              // [128][68]
    float* ML = (float*)(smem + 34816);    // [128]
    const int baserow = qs * 64 + low;
#pragma unroll 1
    for (int src = 1; src < 4; ++src) {
        __syncthreads();
        if (kq == src) {
#pragma unroll
            for (int qf = 0; qf < 4; ++qf) {
                const int row = baserow + qf * 16;
#pragma unroll
                for (int dt = 0; dt < 4; ++dt)
                    *(f32x4*)&MO[row * 68 + dt * 16 + h * 4] = o[qf][dt];
                if (h == 0) ML[row] = lsum[qf];
            }
        }
        __syncthreads();
        if (kq == 0) {
#pragma unroll
            for (int qf = 0; qf < 4; ++qf) {
                const int row = baserow + qf * 16;
#pragma unroll
                for (int dt = 0; dt < 4; ++dt) {
                    f32x4 a = *(const f32x4*)&MO[row * 68 + dt * 16 + h * 4];
#pragma unroll
                    for (int j = 0; j < 4; ++j) o[qf][dt][j] += a[j];
                }
                lsum[qf] += ML[row];
            }
        }
    }

    if (kq == 0) {
#pragma unroll
        for (int qf = 0; qf < 4; ++qf) {
            const float inv = 1.f / lsum[qf];
            float* orow = Out + ((size_t)(batch * S_LEN + qtile * BQ + qs * 64 + qf * 16 + low)) * DHEAD;
#pragma unroll
            for (int dt = 0; dt < 4; ++dt) {
                f32x4 r;
#pragma unroll
                for (int j = 0; j < 4; ++j) r[j] = o[qf][dt][j] * inv;
                *(f32x4*)(orow + dt * 16 + h * 4) = r;
            }
        }
    }
}

// ---------------------------------------------------------------------------
extern "C" void kernel_launch(void* const* d_in, const int* in_sizes, int n_in,
                              void* d_out, int out_size, void* d_ws, size_t ws_size,
                              hipStream_t stream) {
    const float* Q  = (const float*)d_in[0];
    const float* K  = (const float*)d_in[1];
    const float* V  = (const float*)d_in[2];
    const float* cr = (const float*)d_in[3];
    const float* ci = (const float*)d_in[4];
    const float* sc = (const float*)d_in[5];
    float* out = (float*)d_out;

    char* ws = (char*)d_ws;
    float* bias2 = (float*)ws;                                    // 32 KB (+pad)
    u16*   Kb    = (u16*)(ws + 32768);                            // 4 MB
    u16*   Vt    = (u16*)(ws + 32768 + (size_t)NBATCH * S_LEN * DHEAD * 2);

    prep_kernel<<<dim3(1056), dim3(256), 0, stream>>>(K, V, cr, ci, sc, Kb, Vt, bias2);
    flash_kernel<<<dim3(256), dim3(512), 0, stream>>>(Q, Kb, Vt, bias2, out);
}

// Round 6
// 167.343 us; speedup vs baseline: 1.2475x; 1.2475x over previous
//
#include <hip/hip_runtime.h>
#include <math.h>

#define S_LEN 8192
#define DHEAD 64
#define NBATCH 4
#define BK 32
#define KIT 64            // 2048 keys per kq-quarter / BK

typedef unsigned short u16;
typedef unsigned int u32;
typedef __attribute__((ext_vector_type(8))) short short8;
typedef __attribute__((ext_vector_type(4))) float f32x4;

union U16x8 { int4 i4; short8 s8; u32 w[4]; };

#if __has_builtin(__builtin_amdgcn_exp2f)
#define EXP2(x) __builtin_amdgcn_exp2f(x)
#else
#define EXP2(x) exp2f(x)
#endif

// float -> bf16 RNE (prep path only)
__device__ __forceinline__ u16 f2b(float f) {
    u32 u = __float_as_uint(f);
    u32 r = (u + 0x7fffu + ((u >> 16) & 1u)) >> 16;
    return (u16)r;
}

// two floats -> packed bf16x2 (a low), round-half-up: 2 add + 1 perm
__device__ __forceinline__ u32 pack2(float a, float b) {
    u32 ua = __float_as_uint(a) + 0x8000u;
    u32 ub = __float_as_uint(b) + 0x8000u;
    return __builtin_amdgcn_perm(ub, ua, 0x07060302u);
}

// ---------------------------------------------------------------------------
// Prep: blocks [0,1024) pack K,V of one 32-key tile (b = bid>>8, t = bid&255)
// into MFMA-fragment order:
//   blob[b][t] (8 KB) = K chunks j=0..3 (j=kt*2+ds) then V chunks dt=0..3,
//   chunk = 64 lanes x 16 B (8 bf16), exact flash lane order:
//     K: lane(low,h) -> K[b][t*32 + 8*(low>>2)+4*kt+(low&3)][ds*32+h*8+0..7]
//     V: lane(low,h) -> V[b][t*32 + h*8 + 0..7][dt*16+low]
// Blocks [1024,1056): Julia bias in f64 (matches numpy), fixed max M=20
// folded: bias2[k] = log(exp(et*scale)+1e-8)*log2e - 20.
// ---------------------------------------------------------------------------
__global__ void prep_kernel(const float* __restrict__ K, const float* __restrict__ V,
                            const float* crp, const float* cip, const float* scp,
                            u16* __restrict__ blob, float* __restrict__ bias2) {
    int bid = blockIdx.x, tid = threadIdx.x;
    if (bid < 1024) {
        int b = bid >> 8, t = bid & 255;
        __shared__ float Kt[32 * 64];
        __shared__ float Vt[32 * 65];          // padded rows: conflict-free col reads
        int row = tid >> 3, c8 = (tid & 7) * 8;
        const float* ks = K + ((size_t)(b * S_LEN + t * 32 + row)) * 64 + c8;
        const float* vs = V + ((size_t)(b * S_LEN + t * 32 + row)) * 64 + c8;
        float4 ka = *(const float4*)ks, kb4 = *(const float4*)(ks + 4);
        float4 va = *(const float4*)vs, vb4 = *(const float4*)(vs + 4);
        *(float4*)&Kt[row * 64 + c8] = ka;
        *(float4*)&Kt[row * 64 + c8 + 4] = kb4;
        float* vr = &Vt[row * 65 + c8];
        vr[0] = va.x; vr[1] = va.y; vr[2] = va.z; vr[3] = va.w;
        vr[4] = vb4.x; vr[5] = vb4.y; vr[6] = vb4.z; vr[7] = vb4.w;
        __syncthreads();

        int j = tid >> 6, lane = tid & 63, low = lane & 15, h = lane >> 4;
        u16* tb = blob + ((size_t)(b * 256 + t)) * 4096;   // u16 elems (8 KB)
        {   // K chunk j = kt*2 + ds
            int kt = j >> 1, ds = j & 1;
            int krow = 8 * (low >> 2) + 4 * kt + (low & 3);
            const float* src = &Kt[krow * 64 + ds * 32 + h * 8];
            u32 wds[4];
#pragma unroll
            for (int i = 0; i < 4; ++i)
                wds[i] = (u32)f2b(src[2 * i]) | ((u32)f2b(src[2 * i + 1]) << 16);
            *(int4*)(tb + j * 512 + lane * 8) = make_int4(wds[0], wds[1], wds[2], wds[3]);
        }
        {   // V chunk dt = j
            int col = j * 16 + low;
            u32 wds[4];
#pragma unroll
            for (int i = 0; i < 4; ++i) {
                float a = Vt[(h * 8 + 2 * i) * 65 + col];
                float c = Vt[(h * 8 + 2 * i + 1) * 65 + col];
                wds[i] = (u32)f2b(a) | ((u32)f2b(c) << 16);
            }
            *(int4*)(tb + 2048 + j * 512 + lane * 8) = make_int4(wds[0], wds[1], wds[2], wds[3]);
        }
    } else {
#pragma clang fp contract(off)
        int i = (bid - 1024) * 256 + tid;
        double cr = (double)crp[0], ci = (double)cip[0], sc = (double)scp[0];
        double step = 4.0 / (double)(S_LEN - 1);
        double x = (i == S_LEN - 1) ? 2.0 : (-2.0 + step * (double)i);
        double zr = x, zi = 0.0, et = 1.0;
        bool esc = false;
        for (int it = 0; it < 64; ++it) {
            double nzr = zr * zr - zi * zi + cr;
            double nzi = 2.0 * zr * zi + ci;
            if (!esc) { zr = nzr; zi = nzi; }
            double m2 = zr * zr + zi * zi;
            if (!esc && m2 > 4.0) { et = (double)it / 64.0; esc = true; }
        }
        double bias = log(exp(et * sc) + 1e-8);
        bias2[i] = (float)(bias * 1.4426950408889634 - 20.0);
    }
}

// ---------------------------------------------------------------------------
// Flash: packed-fragment streaming, no LDS / no barriers in the main loop.
//   grid 512 (2 blocks/CU), block 512 = 8 waves = 4 kq x 2 qs (scalarized via
//   readfirstlane -> SGPR stream bases); wave = 32 q-rows x 2048 keys, BK=32.
//   All loads are coalesced dwordx4 from the fragment-packed blob.
//   Fixed-max softmax (M=20 in bias); split-K merge by plain adds at the end.
// ---------------------------------------------------------------------------
__global__ __launch_bounds__(512, 4)
void flash_kernel(const float* __restrict__ Q, const u16* __restrict__ blob,
                  const float* __restrict__ bias2, float* __restrict__ Out) {
    __shared__ __align__(16) char smem[18432];   // merge scratch only

    const int tid = threadIdx.x;
    const int l = tid & 63, low = l & 15, h = l >> 4;
    const int kq = __builtin_amdgcn_readfirstlane((tid >> 6) & 3);
    const int qs = __builtin_amdgcn_readfirstlane(tid >> 8);

    const int bid = blockIdx.x;
    const int batch = bid & 3;          // XCD-affinity: batch b on XCDs {b, b+4}
    const int qtile = bid >> 2;         // 0..127 (BQ = 64)
    const int q0 = qtile * 64 + qs * 32;

    // ---- Q fragments (2 x 16 q-rows), scale log2(e)/8 folded ----
    const float qscale = 0.18033688011112042f;
    short8 qfrag[2][2];
#pragma unroll
    for (int qf = 0; qf < 2; ++qf) {
        const float* qrow = Q + ((size_t)(batch * S_LEN + q0 + qf * 16 + low)) * DHEAD + h * 8;
#pragma unroll
        for (int ds = 0; ds < 2; ++ds) {
            f32x4 a = *(const f32x4*)(qrow + ds * 32);
            f32x4 b = *(const f32x4*)(qrow + ds * 32 + 4);
            U16x8 u;
#pragma unroll
            for (int jj = 0; jj < 4; ++jj) {
                u.s8[jj]     = (short)f2b(a[jj] * qscale);
                u.s8[4 + jj] = (short)f2b(b[jj] * qscale);
            }
            qfrag[qf][ds] = u.s8;
        }
    }

    // wave-uniform stream base (SGPR) + single lane offset (VGPR)
    const u16* kvb = blob + ((size_t)(batch * 256 + kq * 64)) * 4096;
    const int loff = l * 8;                         // u16 elems (16 B/lane)
    const float* bbase = bias2 + kq * 2048;

    f32x4 o[2][4];
#pragma unroll
    for (int qf = 0; qf < 2; ++qf)
#pragma unroll
        for (int dt = 0; dt < 4; ++dt) o[qf][dt] = (f32x4){0, 0, 0, 0};
    float lsum[2] = {0.f, 0.f};

#pragma unroll 1
    for (int ki = 0; ki < KIT; ++ki) {
        const u16* tb = kvb + ki * 4096;
        // coalesced fragment loads (compiler: SGPR base + voffset, imm offs)
        U16x8 kf[4], vf[4];
#pragma unroll
        for (int j = 0; j < 4; ++j) kf[j].i4 = *(const int4*)(tb + j * 512 + loff);
#pragma unroll
        for (int j = 0; j < 4; ++j) vf[j].i4 = *(const int4*)(tb + 2048 + j * 512 + loff);
        const float* bp = bbase + ki * 32 + h * 8;
        f32x4 bv0 = *(const f32x4*)bp;
        f32x4 bv1 = *(const f32x4*)(bp + 4);

        // ---- per-kt: QK (bias as C-init) then softmax (short st liveness) ----
        U16x8 pf[2];
#pragma unroll
        for (int kt = 0; kt < 2; ++kt) {
            const f32x4 binit = kt ? bv1 : bv0;
            f32x4 st[2];
#pragma unroll
            for (int qf = 0; qf < 2; ++qf) {
                f32x4 a = __builtin_amdgcn_mfma_f32_16x16x32_bf16(kf[kt * 2].s8, qfrag[qf][0], binit, 0, 0, 0);
                a = __builtin_amdgcn_mfma_f32_16x16x32_bf16(kf[kt * 2 + 1].s8, qfrag[qf][1], a, 0, 0, 0);
                st[qf] = a;
            }
#pragma unroll
            for (int qf = 0; qf < 2; ++qf) {
                float p0 = EXP2(st[qf][0]), p1 = EXP2(st[qf][1]);
                float p2 = EXP2(st[qf][2]), p3 = EXP2(st[qf][3]);
                lsum[qf] += (p0 + p1) + (p2 + p3);
                pf[qf].w[kt * 2]     = pack2(p0, p1);
                pf[qf].w[kt * 2 + 1] = pack2(p2, p3);
            }
        }

        // ---- O^T += V^T·P^T (K=32), V-frag shared across q-frags ----
#pragma unroll
        for (int dt = 0; dt < 4; ++dt)
#pragma unroll
            for (int qf = 0; qf < 2; ++qf)
                o[qf][dt] = __builtin_amdgcn_mfma_f32_16x16x32_bf16(vf[dt].s8, pf[qf].s8, o[qf][dt], 0, 0, 0);
    }

    // ---- finalize l ----
#pragma unroll
    for (int qf = 0; qf < 2; ++qf) {
        lsum[qf] += __shfl_xor(lsum[qf], 16, 64);
        lsum[qf] += __shfl_xor(lsum[qf], 32, 64);
    }

    // ---- split-K merge: partials add linearly (fixed max). 3 stages. ----
    float* MO = (float*)smem;              // [64][68]
    float* ML = (float*)(smem + 17408);    // [64]
    const int baserow = qs * 32 + low;
#pragma unroll 1
    for (int src = 1; src < 4; ++src) {
        __syncthreads();
        if (kq == src) {
#pragma unroll
            for (int qf = 0; qf < 2; ++qf) {
                const int row = baserow + qf * 16;
#pragma unroll
                for (int dt = 0; dt < 4; ++dt)
                    *(f32x4*)&MO[row * 68 + dt * 16 + h * 4] = o[qf][dt];
                if (h == 0) ML[row] = lsum[qf];
            }
        }
        __syncthreads();
        if (kq == 0) {
#pragma unroll
            for (int qf = 0; qf < 2; ++qf) {
                const int row = baserow + qf * 16;
#pragma unroll
                for (int dt = 0; dt < 4; ++dt) {
                    f32x4 a = *(const f32x4*)&MO[row * 68 + dt * 16 + h * 4];
#pragma unroll
                    for (int jj = 0; jj < 4; ++jj) o[qf][dt][jj] += a[jj];
                }
                lsum[qf] += ML[row];
            }
        }
    }

    if (kq == 0) {
#pragma unroll
        for (int qf = 0; qf < 2; ++qf) {
            const float inv = 1.f / lsum[qf];
            float* orow = Out + ((size_t)(batch * S_LEN + qtile * 64 + qs * 32 + qf * 16 + low)) * DHEAD;
#pragma unroll
            for (int dt = 0; dt < 4; ++dt) {
                f32x4 r;
#pragma unroll
                for (int jj = 0; jj < 4; ++jj) r[jj] = o[qf][dt][jj] * inv;
                *(f32x4*)(orow + dt * 16 + h * 4) = r;
            }
        }
    }
}

// ---------------------------------------------------------------------------
extern "C" void kernel_launch(void* const* d_in, const int* in_sizes, int n_in,
                              void* d_out, int out_size, void* d_ws, size_t ws_size,
                              hipStream_t stream) {
    const float* Q  = (const float*)d_in[0];
    const float* K  = (const float*)d_in[1];
    const float* V  = (const float*)d_in[2];
    const float* cr = (const float*)d_in[3];
    const float* ci = (const float*)d_in[4];
    const float* sc = (const float*)d_in[5];
    float* out = (float*)d_out;

    char* ws = (char*)d_ws;
    float* bias2 = (float*)ws;                 // 32 KB
    u16*   blob  = (u16*)(ws + 32768);         // 8 MB packed K+V fragments

    prep_kernel<<<dim3(1056), dim3(256), 0, stream>>>(K, V, cr, ci, sc, blob, bias2);
    flash_kernel<<<dim3(512), dim3(512), 0, stream>>>(Q, blob, bias2, out);
}